// Round 1
// baseline (57.050 us; speedup 1.0000x reference)
//
#include <hip/hip_runtime.h>

#define H 1024
#define W 1024
#define TILE 32
#define HALO4 40   // TILE + 8 (luma halo, +-4)
#define HALO2 36   // TILE + 4 (weight/rgb halo, +-2)

__global__ __launch_bounds__(256)
void kuwahara_kernel(const float* __restrict__ inp, float* __restrict__ out) {
    __shared__ float  s_lum[HALO4][HALO4];   // zero-padded luma
    __shared__ float2 s_rs [HALO4][HALO2];   // horizontal (sum, sum_sq) of luma
    __shared__ float4 s_vw [HALO2][HALO2];   // (r, g, b, k->weight)

    const int tid = threadIdx.x;
    const int n  = blockIdx.z;
    const int y0 = blockIdx.y * TILE;
    const int x0 = blockIdx.x * TILE;

    const float* __restrict__ pR = inp + ((size_t)(4*n + 0) << 20);
    const float* __restrict__ pG = inp + ((size_t)(4*n + 1) << 20);
    const float* __restrict__ pB = inp + ((size_t)(4*n + 2) << 20);
    const float* __restrict__ pK = inp + ((size_t)(4*n + 3) << 20);

    const int tx  = tid & 31;   // column within tile
    const int tg  = tid >> 5;   // row-group: owns rows 4*tg .. 4*tg+3
    const int gx  = x0 + tx;
    const int pr0 = tg << 2;

    // ---- early global loads: k at this thread's 4 output pixels ----
    float kc[4];
#pragma unroll
    for (int p = 0; p < 4; ++p)
        kc[p] = pK[((y0 + pr0 + p) << 10) + gx];

    float t1[4], t4[4], cb[4];
#pragma unroll
    for (int p = 0; p < 4; ++p) {
        // t = exp(-invwidth/25), invwidth = 64*(1-k)  ->  t^(dy^2+dx^2) spatial factor
        float t = __expf(-2.56f * (1.0f - kc[p]));
        t1[p] = t;
        float t2 = t * t;
        t4[p] = t2 * t2;
        cb[p] = 16.0f + kc[p] * (0.001f - 16.0f);   // center boost
    }

    // ---- stage 1: load halo, luma (zero-padded), rgb+k (edge region) ----
    for (int idx = tid; idx < HALO4 * HALO4; idx += 256) {
        int j  = idx / HALO4;
        int i  = idx - j * HALO4;
        int gy = y0 - 4 + j;
        int gc = x0 - 4 + i;
        bool in = ((unsigned)gy < (unsigned)H) & ((unsigned)gc < (unsigned)W);
        float r = 0.f, g = 0.f, b = 0.f, k = 0.f;
        if (in) {
            int off = (gy << 10) + gc;
            r = pR[off]; g = pG[off]; b = pB[off]; k = pK[off];
        }
        s_lum[j][i] = 0.2126f * r + 0.7152f * g + 0.0722f * b;  // 0 outside image
        if (j >= 2 && j < HALO4 - 2 && i >= 2 && i < HALO4 - 2)
            s_vw[j - 2][i - 2] = make_float4(r, g, b, k);
    }
    __syncthreads();

    // ---- stage 2: horizontal 5-tap sums of luma and luma^2 ----
    for (int idx = tid; idx < HALO4 * HALO2; idx += 256) {
        int j  = idx / HALO2;
        int i2 = idx - j * HALO2;
        float l0 = s_lum[j][i2+0], l1 = s_lum[j][i2+1], l2 = s_lum[j][i2+2];
        float l3 = s_lum[j][i2+3], l4 = s_lum[j][i2+4];
        float s  = ((l0 + l1) + (l2 + l3)) + l4;
        float s2 = ((l0*l0 + l1*l1) + (l2*l2 + l3*l3)) + l4*l4;
        s_rs[j][i2] = make_float2(s, s2);
    }
    __syncthreads();

    // ---- stage 3: vertical 5-tap sums -> variance -> weight into s_vw.w ----
    for (int idx = tid; idx < HALO2 * HALO2; idx += 256) {
        int j2 = idx / HALO2;
        int i2 = idx - j2 * HALO2;
        float2 a = s_rs[j2+0][i2], b = s_rs[j2+1][i2], c = s_rs[j2+2][i2];
        float2 d = s_rs[j2+3][i2], e = s_rs[j2+4][i2];
        float mean = (((a.x + b.x) + (c.x + d.x)) + e.x) * 0.04f;
        float msq  = (((a.y + b.y) + (c.y + d.y)) + e.y) * 0.04f;
        float var  = fabsf(msq - mean * mean);
        float kk   = s_vw[j2][i2].w;                 // k stashed here in stage 1
        s_vw[j2][i2].w = __expf(-var * 64.0f * kk);  // weight
    }
    __syncthreads();

    // ---- stage 4: 25-tap filter, 4 consecutive rows per thread ----
    int i2a[5];
#pragma unroll
    for (int dxi = 0; dxi < 5; ++dxi) {
        int cx = gx + dxi - 2;
        cx = min(max(cx, 0), W - 1);      // edge clamp
        i2a[dxi] = cx - x0 + 2;
    }
    int j2r[8];
#pragma unroll
    for (int r8 = 0; r8 < 8; ++r8) {
        int gy = y0 + pr0 + r8 - 2;
        gy = min(max(gy, 0), H - 1);      // edge clamp
        j2r[r8] = gy - y0 + 2;
    }

    float accR[4], accG[4], accB[4], accW[4];
    float ctrR[4], ctrG[4], ctrB[4];
#pragma unroll
    for (int p = 0; p < 4; ++p) { accR[p] = accG[p] = accB[p] = accW[p] = 0.f; }

#pragma unroll
    for (int r8 = 0; r8 < 8; ++r8) {
        const float4* row = &s_vw[j2r[r8]][0];
        float4 a0 = row[i2a[0]];
        float4 a1 = row[i2a[1]];
        float4 a2 = row[i2a[2]];
        float4 a3 = row[i2a[3]];
        float4 a4 = row[i2a[4]];
#pragma unroll
        for (int p = 0; p < 4; ++p) {
            const int dy = r8 - 2 - p;                  // compile-time after unroll
            if (dy < -2 || dy > 2) continue;
            const int ady = dy < 0 ? -dy : dy;
            float rf = (ady == 0) ? 1.0f : (ady == 1 ? t1[p] : t4[p]);
            if (dy == 0) { ctrR[p] = a2.x; ctrG[p] = a2.y; ctrB[p] = a2.z; }
            float f1 = rf * t1[p];   // |dx| = 1
            float f0 = rf * t4[p];   // |dx| = 2
            float w;
            w = a0.w * f0; accR[p] += a0.x*w; accG[p] += a0.y*w; accB[p] += a0.z*w; accW[p] += w;
            w = a1.w * f1; accR[p] += a1.x*w; accG[p] += a1.y*w; accB[p] += a1.z*w; accW[p] += w;
            w = a2.w * rf; if (dy == 0) w += cb[p];
                           accR[p] += a2.x*w; accG[p] += a2.y*w; accB[p] += a2.z*w; accW[p] += w;
            w = a3.w * f1; accR[p] += a3.x*w; accG[p] += a3.y*w; accB[p] += a3.z*w; accW[p] += w;
            w = a4.w * f0; accR[p] += a4.x*w; accG[p] += a4.y*w; accB[p] += a4.z*w; accW[p] += w;
        }
    }

    float* __restrict__ oR = out + ((size_t)(3*n + 0) << 20);
    float* __restrict__ oG = out + ((size_t)(3*n + 1) << 20);
    float* __restrict__ oB = out + ((size_t)(3*n + 2) << 20);
#pragma unroll
    for (int p = 0; p < 4; ++p) {
        float inv = 1.0f / accW[p];
        int off = ((y0 + pr0 + p) << 10) + gx;
        oR[off] = ctrR[p] + kc[p] * (accR[p] * inv - ctrR[p]);
        oG[off] = ctrG[p] + kc[p] * (accG[p] * inv - ctrG[p]);
        oB[off] = ctrB[p] + kc[p] * (accB[p] * inv - ctrB[p]);
    }
}

extern "C" void kernel_launch(void* const* d_in, const int* in_sizes, int n_in,
                              void* d_out, int out_size, void* d_ws, size_t ws_size,
                              hipStream_t stream) {
    const float* inp = (const float*)d_in[0];
    float* out = (float*)d_out;
    dim3 grid(W / TILE, H / TILE, 4);
    hipLaunchKernelGGL(kuwahara_kernel, grid, dim3(256), 0, stream, inp, out);
}